// Round 2
// baseline (943.067 us; speedup 1.0000x reference)
//
#include <hip/hip_runtime.h>

#define NN 20000      // nodes
#define NE 320000     // edges
#define SS 2          // feature axis
#define FIN 128
#define FH 246

// ---------------- degree histogram ----------------
__global__ void degree_kernel(const int* __restrict__ src, const int* __restrict__ dst,
                              int* __restrict__ deg_out, int* __restrict__ deg_in) {
    int e = blockIdx.x * blockDim.x + threadIdx.x;
    if (e < NE) {
        atomicAdd(&deg_out[src[e]], 1);
        atomicAdd(&deg_in[dst[e]], 1);
    }
}

// ---------------- norms ----------------
__global__ void norm_kernel(const int* __restrict__ deg_out, const int* __restrict__ deg_in,
                            float* __restrict__ norm_out, float* __restrict__ norm_in) {
    int n = blockIdx.x * blockDim.x + threadIdx.x;
    if (n < NN) {
        norm_out[n] = rsqrtf(fmaxf((float)deg_out[n], 1.0f));
        norm_in[n]  = rsqrtf(fmaxf((float)deg_in[n], 1.0f));
    }
}

// ---------------- exclusive scan of in-degrees -> row_ptr (single block) ----------------
__global__ void scan_kernel(const int* __restrict__ deg_in, int* __restrict__ row_ptr,
                            int* __restrict__ cursor) {
    __shared__ int smem[256];
    __shared__ int carry_s;
    int tid = threadIdx.x;
    if (tid == 0) carry_s = 0;
    __syncthreads();
    for (int base = 0; base < NN; base += 256) {
        int i = base + tid;
        int v = (i < NN) ? deg_in[i] : 0;
        smem[tid] = v;
        __syncthreads();
        for (int off = 1; off < 256; off <<= 1) {
            int t = (tid >= off) ? smem[tid - off] : 0;
            __syncthreads();
            smem[tid] += t;
            __syncthreads();
        }
        int incl  = smem[tid];
        int total = smem[255];
        int carry = carry_s;
        if (i < NN) {
            int excl = carry + incl - v;
            row_ptr[i] = excl;
            cursor[i]  = excl;
        }
        __syncthreads();
        if (tid == 0) carry_s = carry + total;
        __syncthreads();
    }
    if (tid == 0) row_ptr[NN] = carry_s;
}

// ---------------- scatter edges into CSR ----------------
__global__ void scatter_kernel(const int* __restrict__ src, const int* __restrict__ dst,
                               int* __restrict__ cursor, int* __restrict__ sorted_src) {
    int e = blockIdx.x * blockDim.x + threadIdx.x;
    if (e < NE) {
        int d = dst[e];
        int pos = atomicAdd(&cursor[d], 1);
        sorted_src[pos] = src[e];
    }
}

// ---------------- per-dst gather-aggregate: agg[n,s,f] = sum_{e: dst=n} h[src,s,f]*norm_out[src]
template<int F>
__global__ void aggregate_kernel(const float* __restrict__ h,
                                 const int* __restrict__ row_ptr,
                                 const int* __restrict__ sorted_src,
                                 const float* __restrict__ norm_out,
                                 float* __restrict__ agg) {
    int n = blockIdx.x;
    int f = threadIdx.x;
    int beg = row_ptr[n], end = row_ptr[n + 1];
    float acc0 = 0.f, acc1 = 0.f;
    for (int i = beg; i < end; ++i) {
        int s = sorted_src[i];
        float nrm = norm_out[s];
        if (f < F) {
            const float* hp = h + (size_t)s * (2 * F);
            acc0 += hp[f]     * nrm;
            acc1 += hp[F + f] * nrm;
        }
    }
    if (f < F) {
        float* ap = agg + (size_t)n * (2 * F);
        ap[f]     = acc0;
        ap[F + f] = acc1;
    }
}

// ---------------- register-tiled GEMM ----------------
// out[m,j] = relu( (A[m,:]*norm_in[m/2]) . W[:,j] + b[j] ), j in [0,246)
// BM=64 rows/block, BN=256 cols (covers 246), BK=16.
// 256 threads: tx = tid&63 -> cols 4*tx..4*tx+3 ; ty = tid>>6 -> rows 16*ty..16*ty+15.
// A staged transposed in LDS so inner loop is all ds_read_b128.
template<int K>
__global__ __launch_bounds__(256) void gemm_kernel(const float* __restrict__ A,
                                                   const float* __restrict__ W,
                                                   const float* __restrict__ b,
                                                   const float* __restrict__ norm_in,
                                                   float* __restrict__ out) {
    constexpr int BM = 64, BK = 16;
    __shared__ float A_s[BK][BM + 4];   // +4 pad: keeps 16B alignment, 2-way-only write conflicts
    __shared__ float W_s[BK][256];

    int tid = threadIdx.x;
    int m0  = blockIdx.x * BM;
    int tx  = tid & 63;
    int ty  = tid >> 6;

    float acc[16][4];
#pragma unroll
    for (int r = 0; r < 16; ++r)
#pragma unroll
        for (int c = 0; c < 4; ++c) acc[r][c] = 0.f;

    for (int kt = 0; kt < K; kt += BK) {
        // ---- stage A (64 rows x 16 k), transposed, norm_in fused. 1 float4/thread.
        {
            int r  = tid >> 2;          // 0..63
            int kk = (tid & 3) * 4;     // 0,4,8,12
            int m  = m0 + r;
            int kg = kt + kk;
            float4 v;
            if (kg + 3 < K) {
                v = *(const float4*)(A + (size_t)m * K + kg);
            } else {
                v.x = (kg + 0 < K) ? A[(size_t)m * K + kg + 0] : 0.f;
                v.y = (kg + 1 < K) ? A[(size_t)m * K + kg + 1] : 0.f;
                v.z = (kg + 2 < K) ? A[(size_t)m * K + kg + 2] : 0.f;
                v.w = (kg + 3 < K) ? A[(size_t)m * K + kg + 3] : 0.f;
            }
            float nrm = norm_in[m >> 1];
            A_s[kk + 0][r] = v.x * nrm;
            A_s[kk + 1][r] = v.y * nrm;
            A_s[kk + 2][r] = v.z * nrm;
            A_s[kk + 3][r] = v.w * nrm;
        }
        // ---- stage W (16 k x 246 cols, zero-pad to 256)
#pragma unroll
        for (int it = 0; it < BK; ++it) {
            int idx = it * 256 + tid;
            int k = idx >> 8;
            int c = idx & 255;
            int kg = kt + k;
            W_s[k][c] = (c < 246 && kg < K) ? W[(size_t)kg * 246 + c] : 0.f;
        }
        __syncthreads();

#pragma unroll
        for (int k = 0; k < BK; ++k) {
            float4 a0 = *(const float4*)&A_s[k][16 * ty + 0];
            float4 a1 = *(const float4*)&A_s[k][16 * ty + 4];
            float4 a2 = *(const float4*)&A_s[k][16 * ty + 8];
            float4 a3 = *(const float4*)&A_s[k][16 * ty + 12];
            float4 w  = *(const float4*)&W_s[k][4 * tx];
            float av[16] = {a0.x, a0.y, a0.z, a0.w, a1.x, a1.y, a1.z, a1.w,
                            a2.x, a2.y, a2.z, a2.w, a3.x, a3.y, a3.z, a3.w};
#pragma unroll
            for (int r = 0; r < 16; ++r) {
                acc[r][0] += av[r] * w.x;
                acc[r][1] += av[r] * w.y;
                acc[r][2] += av[r] * w.z;
                acc[r][3] += av[r] * w.w;
            }
        }
        __syncthreads();
    }

    // ---- epilogue: bias + relu + store (cols >= 246 dropped)
    int c0 = 4 * tx;
    float4 bj;
    bj.x = (c0 + 0 < 246) ? b[c0 + 0] : 0.f;
    bj.y = (c0 + 1 < 246) ? b[c0 + 1] : 0.f;
    bj.z = (c0 + 2 < 246) ? b[c0 + 2] : 0.f;
    bj.w = (c0 + 3 < 246) ? b[c0 + 3] : 0.f;
#pragma unroll
    for (int r = 0; r < 16; ++r) {
        int m = m0 + 16 * ty + r;
        float* op = out + (size_t)m * 246 + c0;
        float v0 = fmaxf(acc[r][0] + bj.x, 0.f);
        float v1 = fmaxf(acc[r][1] + bj.y, 0.f);
        float v2 = fmaxf(acc[r][2] + bj.z, 0.f);
        float v3 = fmaxf(acc[r][3] + bj.w, 0.f);
        if (c0 + 3 < 246) {
            float4 v = {v0, v1, v2, v3};
            *(float4*)op = v;
        } else {
            if (c0 + 0 < 246) op[0] = v0;
            if (c0 + 1 < 246) op[1] = v1;
            if (c0 + 2 < 246) op[2] = v2;
            if (c0 + 3 < 246) op[3] = v3;
        }
    }
}

// ---------------- epilogue: out[n] = mean_s(h[n,s,:]) . fc_w + fc_b ----------------
__global__ void final_kernel(const float* __restrict__ h,
                             const float* __restrict__ fcw, const float* __restrict__ fcb,
                             float* __restrict__ out) {
    int n = blockIdx.x;
    int lane = threadIdx.x;
    float acc = 0.f;
    for (int f = lane; f < FH; f += 64) {
        acc += (h[(size_t)n * (2 * FH) + f] + h[(size_t)n * (2 * FH) + FH + f]) * fcw[f];
    }
#pragma unroll
    for (int off = 32; off > 0; off >>= 1)
        acc += __shfl_down(acc, off, 64);
    if (lane == 0) out[n] = 0.5f * acc + fcb[0];
}

extern "C" void kernel_launch(void* const* d_in, const int* in_sizes, int n_in,
                              void* d_out, int out_size, void* d_ws, size_t ws_size,
                              hipStream_t stream) {
    const float* feat = (const float*)d_in[0];
    const int*   src  = (const int*)d_in[1];
    const int*   dst  = (const int*)d_in[2];
    const float* W0   = (const float*)d_in[3];
    const float* b0   = (const float*)d_in[4];
    const float* W1   = (const float*)d_in[5];
    const float* b1   = (const float*)d_in[6];
    const float* W2   = (const float*)d_in[7];
    const float* b2   = (const float*)d_in[8];
    const float* fcw  = (const float*)d_in[9];
    const float* fcb  = (const float*)d_in[10];
    float* out = (float*)d_out;

    char* ws = (char*)d_ws;
    size_t off = 0;
    auto alloc = [&](size_t bytes) {
        void* p = ws + off;
        off = (off + bytes + 255) & ~(size_t)255;
        return p;
    };
    int*   deg_out_i = (int*)alloc(2 * NN * sizeof(int));   // deg_out + deg_in adjacent
    int*   deg_in_i  = deg_out_i + NN;
    int*   row_ptr   = (int*)alloc((NN + 1) * sizeof(int));
    int*   cursor    = (int*)alloc(NN * sizeof(int));
    int*   sorted    = (int*)alloc(NE * sizeof(int));
    float* norm_out  = (float*)alloc(NN * sizeof(float));
    float* norm_in   = (float*)alloc(NN * sizeof(float));
    float* bufA      = (float*)alloc((size_t)NN * SS * FH * sizeof(float));
    float* bufB      = (float*)alloc((size_t)NN * SS * FH * sizeof(float));

    // zero degree counters (ws is poisoned 0xAA before every call)
    hipMemsetAsync(deg_out_i, 0, 2 * NN * sizeof(int), stream);

    degree_kernel<<<(NE + 255) / 256, 256, 0, stream>>>(src, dst, deg_out_i, deg_in_i);
    norm_kernel<<<(NN + 255) / 256, 256, 0, stream>>>(deg_out_i, deg_in_i, norm_out, norm_in);
    scan_kernel<<<1, 256, 0, stream>>>(deg_in_i, row_ptr, cursor);
    scatter_kernel<<<(NE + 255) / 256, 256, 0, stream>>>(src, dst, cursor, sorted);

    // Layer 0: features [N,S,128] -> agg(bufA) -> gemm -> h1(bufB) [N,S,246]
    aggregate_kernel<FIN><<<NN, 128, 0, stream>>>(feat, row_ptr, sorted, norm_out, bufA);
    gemm_kernel<FIN><<<(NN * SS) / 64, 256, 0, stream>>>(bufA, W0, b0, norm_in, bufB);

    // Layer 1
    aggregate_kernel<FH><<<NN, 256, 0, stream>>>(bufB, row_ptr, sorted, norm_out, bufA);
    gemm_kernel<FH><<<(NN * SS) / 64, 256, 0, stream>>>(bufA, W1, b1, norm_in, bufB);

    // Layer 2
    aggregate_kernel<FH><<<NN, 256, 0, stream>>>(bufB, row_ptr, sorted, norm_out, bufA);
    gemm_kernel<FH><<<(NN * SS) / 64, 256, 0, stream>>>(bufA, W2, b2, norm_in, bufB);

    // Epilogue
    final_kernel<<<NN, 64, 0, stream>>>(bufB, fcw, fcb, out);
}

// Round 3
// 658.327 us; speedup vs baseline: 1.4325x; 1.4325x over previous
//
#include <hip/hip_runtime.h>

#define NN 20000      // nodes
#define NE 320000     // edges
#define SS 2          // feature axis
#define FIN 128
#define FH 246

// ---------------- degree histogram ----------------
__global__ void degree_kernel(const int* __restrict__ src, const int* __restrict__ dst,
                              int* __restrict__ deg_out, int* __restrict__ deg_in) {
    int e = blockIdx.x * blockDim.x + threadIdx.x;
    if (e < NE) {
        atomicAdd(&deg_out[src[e]], 1);
        atomicAdd(&deg_in[dst[e]], 1);
    }
}

// ---------------- norms ----------------
__global__ void norm_kernel(const int* __restrict__ deg_out, const int* __restrict__ deg_in,
                            float* __restrict__ norm_out, float* __restrict__ norm_in) {
    int n = blockIdx.x * blockDim.x + threadIdx.x;
    if (n < NN) {
        norm_out[n] = rsqrtf(fmaxf((float)deg_out[n], 1.0f));
        norm_in[n]  = rsqrtf(fmaxf((float)deg_in[n], 1.0f));
    }
}

// ---------------- exclusive scan of in-degrees -> row_ptr (single block) ----------------
__global__ void scan_kernel(const int* __restrict__ deg_in, int* __restrict__ row_ptr,
                            int* __restrict__ cursor) {
    __shared__ int smem[256];
    __shared__ int carry_s;
    int tid = threadIdx.x;
    if (tid == 0) carry_s = 0;
    __syncthreads();
    for (int base = 0; base < NN; base += 256) {
        int i = base + tid;
        int v = (i < NN) ? deg_in[i] : 0;
        smem[tid] = v;
        __syncthreads();
        for (int off = 1; off < 256; off <<= 1) {
            int t = (tid >= off) ? smem[tid - off] : 0;
            __syncthreads();
            smem[tid] += t;
            __syncthreads();
        }
        int incl  = smem[tid];
        int total = smem[255];
        int carry = carry_s;
        if (i < NN) {
            int excl = carry + incl - v;
            row_ptr[i] = excl;
            cursor[i]  = excl;
        }
        __syncthreads();
        if (tid == 0) carry_s = carry + total;
        __syncthreads();
    }
    if (tid == 0) row_ptr[NN] = carry_s;
}

// ---------------- scatter edges into CSR ----------------
__global__ void scatter_kernel(const int* __restrict__ src, const int* __restrict__ dst,
                               int* __restrict__ cursor, int* __restrict__ sorted_src) {
    int e = blockIdx.x * blockDim.x + threadIdx.x;
    if (e < NE) {
        int d = dst[e];
        int pos = atomicAdd(&cursor[d], 1);
        sorted_src[pos] = src[e];
    }
}

// ---------------- per-dst gather-aggregate: agg[n,s,f] = sum_{e: dst=n} h[src,s,f]*norm_out[src]
template<int F>
__global__ void aggregate_kernel(const float* __restrict__ h,
                                 const int* __restrict__ row_ptr,
                                 const int* __restrict__ sorted_src,
                                 const float* __restrict__ norm_out,
                                 float* __restrict__ agg) {
    int n = blockIdx.x;
    int f = threadIdx.x;
    int beg = row_ptr[n], end = row_ptr[n + 1];
    float acc0 = 0.f, acc1 = 0.f;
    for (int i = beg; i < end; ++i) {
        int s = sorted_src[i];
        float nrm = norm_out[s];
        if (f < F) {
            const float* hp = h + (size_t)s * (2 * F);
            acc0 += hp[f]     * nrm;
            acc1 += hp[F + f] * nrm;
        }
    }
    if (f < F) {
        float* ap = agg + (size_t)n * (2 * F);
        ap[f]     = acc0;
        ap[F + f] = acc1;
    }
}

// ---------------- register-tiled GEMM ----------------
// out[m,j] = relu( (A[m,:]*norm_in[m/2]) . W[:,j] + b[j] ), j in [0,246)
// BM=64 rows, BN=128 cols per block -> grid (625, 2) = 1250 blocks.
// 256 threads, thread tile 8 rows x 4 cols.
// Inner loop per k: 2 b128 A-reads (broadcast) + 1 b128 W-read + 32 FMA.
template<int K>
__global__ __launch_bounds__(256) void gemm_kernel(const float* __restrict__ A,
                                                   const float* __restrict__ W,
                                                   const float* __restrict__ b,
                                                   const float* __restrict__ norm_in,
                                                   float* __restrict__ out) {
    constexpr int BM = 64, BN = 128, BK = 16;
    __shared__ float A_s[BK][BM + 4];   // transposed; 68-float rows keep 16B alignment
    __shared__ float W_s[BK][BN];

    int tid = threadIdx.x;
    int m0  = blockIdx.x * BM;
    int cb  = blockIdx.y * BN;     // 0 or 128
    int tx  = tid & 31;            // cols cb + 4*tx .. +3
    int ty  = tid >> 5;            // rows m0 + 8*ty .. +7

    float acc[8][4];
#pragma unroll
    for (int r = 0; r < 8; ++r)
#pragma unroll
        for (int c = 0; c < 4; ++c) acc[r][c] = 0.f;

    for (int kt = 0; kt < K; kt += BK) {
        // ---- stage A (64 rows x 16 k), transposed, norm_in fused. 1 float4/thread.
        {
            int r  = tid >> 2;          // 0..63
            int kk = (tid & 3) * 4;     // 0,4,8,12
            int m  = m0 + r;
            int kg = kt + kk;
            float4 v;
            if (kg + 3 < K) {
                v = *(const float4*)(A + (size_t)m * K + kg);
            } else {
                v.x = (kg + 0 < K) ? A[(size_t)m * K + kg + 0] : 0.f;
                v.y = (kg + 1 < K) ? A[(size_t)m * K + kg + 1] : 0.f;
                v.z = (kg + 2 < K) ? A[(size_t)m * K + kg + 2] : 0.f;
                v.w = (kg + 3 < K) ? A[(size_t)m * K + kg + 3] : 0.f;
            }
            float nrm = norm_in[m >> 1];
            A_s[kk + 0][r] = v.x * nrm;
            A_s[kk + 1][r] = v.y * nrm;
            A_s[kk + 2][r] = v.z * nrm;
            A_s[kk + 3][r] = v.w * nrm;
        }
        // ---- stage W (16 k x 128 cols): 2 float4 loads/thread, coalesced
#pragma unroll
        for (int it = 0; it < 2; ++it) {
            int idx = it * 256 + tid;
            int k   = idx >> 5;          // 0..15
            int c4  = (idx & 31) * 4;    // 0..124
            int kg  = kt + k;
            int cc  = cb + c4;
            float4 w;
            if (kg < K) {
                if (cc + 3 < 246) {
                    w = *(const float4*)(W + (size_t)kg * 246 + cc);
                } else {
                    w.x = (cc + 0 < 246) ? W[(size_t)kg * 246 + cc + 0] : 0.f;
                    w.y = (cc + 1 < 246) ? W[(size_t)kg * 246 + cc + 1] : 0.f;
                    w.z = (cc + 2 < 246) ? W[(size_t)kg * 246 + cc + 2] : 0.f;
                    w.w = 0.f;
                }
            } else {
                w.x = w.y = w.z = w.w = 0.f;
            }
            *(float4*)&W_s[k][c4] = w;
        }
        __syncthreads();

#pragma unroll
        for (int k = 0; k < BK; ++k) {
            float4 a0 = *(const float4*)&A_s[k][8 * ty + 0];
            float4 a1 = *(const float4*)&A_s[k][8 * ty + 4];
            float4 w  = *(const float4*)&W_s[k][4 * tx];
            float av[8] = {a0.x, a0.y, a0.z, a0.w, a1.x, a1.y, a1.z, a1.w};
#pragma unroll
            for (int r = 0; r < 8; ++r) {
                acc[r][0] += av[r] * w.x;
                acc[r][1] += av[r] * w.y;
                acc[r][2] += av[r] * w.z;
                acc[r][3] += av[r] * w.w;
            }
        }
        __syncthreads();
    }

    // ---- epilogue: bias + relu + store (cols >= 246 dropped)
    int c0 = cb + 4 * tx;
    float4 bj;
    bj.x = (c0 + 0 < 246) ? b[c0 + 0] : 0.f;
    bj.y = (c0 + 1 < 246) ? b[c0 + 1] : 0.f;
    bj.z = (c0 + 2 < 246) ? b[c0 + 2] : 0.f;
    bj.w = (c0 + 3 < 246) ? b[c0 + 3] : 0.f;
#pragma unroll
    for (int r = 0; r < 8; ++r) {
        int m = m0 + 8 * ty + r;
        float* op = out + (size_t)m * 246 + c0;
        float v0 = fmaxf(acc[r][0] + bj.x, 0.f);
        float v1 = fmaxf(acc[r][1] + bj.y, 0.f);
        float v2 = fmaxf(acc[r][2] + bj.z, 0.f);
        float v3 = fmaxf(acc[r][3] + bj.w, 0.f);
        if (c0 + 3 < 246) {
            float4 v = {v0, v1, v2, v3};
            *(float4*)op = v;
        } else {
            if (c0 + 0 < 246) op[0] = v0;
            if (c0 + 1 < 246) op[1] = v1;
            if (c0 + 2 < 246) op[2] = v2;
        }
    }
}

// ---------------- epilogue: out[n] = mean_s(h[n,s,:]) . fc_w + fc_b ----------------
__global__ void final_kernel(const float* __restrict__ h,
                             const float* __restrict__ fcw, const float* __restrict__ fcb,
                             float* __restrict__ out) {
    int n = blockIdx.x;
    int lane = threadIdx.x;
    float acc = 0.f;
    for (int f = lane; f < FH; f += 64) {
        acc += (h[(size_t)n * (2 * FH) + f] + h[(size_t)n * (2 * FH) + FH + f]) * fcw[f];
    }
#pragma unroll
    for (int off = 32; off > 0; off >>= 1)
        acc += __shfl_down(acc, off, 64);
    if (lane == 0) out[n] = 0.5f * acc + fcb[0];
}

extern "C" void kernel_launch(void* const* d_in, const int* in_sizes, int n_in,
                              void* d_out, int out_size, void* d_ws, size_t ws_size,
                              hipStream_t stream) {
    const float* feat = (const float*)d_in[0];
    const int*   src  = (const int*)d_in[1];
    const int*   dst  = (const int*)d_in[2];
    const float* W0   = (const float*)d_in[3];
    const float* b0   = (const float*)d_in[4];
    const float* W1   = (const float*)d_in[5];
    const float* b1   = (const float*)d_in[6];
    const float* W2   = (const float*)d_in[7];
    const float* b2   = (const float*)d_in[8];
    const float* fcw  = (const float*)d_in[9];
    const float* fcb  = (const float*)d_in[10];
    float* out = (float*)d_out;

    char* ws = (char*)d_ws;
    size_t off = 0;
    auto alloc = [&](size_t bytes) {
        void* p = ws + off;
        off = (off + bytes + 255) & ~(size_t)255;
        return p;
    };
    int*   deg_out_i = (int*)alloc(2 * NN * sizeof(int));   // deg_out + deg_in adjacent
    int*   deg_in_i  = deg_out_i + NN;
    int*   row_ptr   = (int*)alloc((NN + 1) * sizeof(int));
    int*   cursor    = (int*)alloc(NN * sizeof(int));
    int*   sorted    = (int*)alloc(NE * sizeof(int));
    float* norm_out  = (float*)alloc(NN * sizeof(float));
    float* norm_in   = (float*)alloc(NN * sizeof(float));
    float* bufA      = (float*)alloc((size_t)NN * SS * FH * sizeof(float));
    float* bufB      = (float*)alloc((size_t)NN * SS * FH * sizeof(float));

    // zero degree counters (ws is poisoned 0xAA before every call)
    hipMemsetAsync(deg_out_i, 0, 2 * NN * sizeof(int), stream);

    degree_kernel<<<(NE + 255) / 256, 256, 0, stream>>>(src, dst, deg_out_i, deg_in_i);
    norm_kernel<<<(NN + 255) / 256, 256, 0, stream>>>(deg_out_i, deg_in_i, norm_out, norm_in);
    scan_kernel<<<1, 256, 0, stream>>>(deg_in_i, row_ptr, cursor);
    scatter_kernel<<<(NE + 255) / 256, 256, 0, stream>>>(src, dst, cursor, sorted);

    dim3 ggrid(NN * SS / 64, 2);

    // Layer 0: features [N,S,128] -> agg(bufA) -> gemm -> h1(bufB) [N,S,246]
    aggregate_kernel<FIN><<<NN, 128, 0, stream>>>(feat, row_ptr, sorted, norm_out, bufA);
    gemm_kernel<FIN><<<ggrid, 256, 0, stream>>>(bufA, W0, b0, norm_in, bufB);

    // Layer 1
    aggregate_kernel<FH><<<NN, 256, 0, stream>>>(bufB, row_ptr, sorted, norm_out, bufA);
    gemm_kernel<FH><<<ggrid, 256, 0, stream>>>(bufA, W1, b1, norm_in, bufB);

    // Layer 2
    aggregate_kernel<FH><<<NN, 256, 0, stream>>>(bufB, row_ptr, sorted, norm_out, bufA);
    gemm_kernel<FH><<<ggrid, 256, 0, stream>>>(bufA, W2, b2, norm_in, bufB);

    // Epilogue
    final_kernel<<<NN, 64, 0, stream>>>(bufB, fcw, fcb, out);
}

// Round 4
// 611.168 us; speedup vs baseline: 1.5431x; 1.0772x over previous
//
#include <hip/hip_runtime.h>

#define NN 20000      // nodes
#define NE 320000     // edges
#define SS 2          // feature axis
#define FIN 128
#define FH 246

// ---------------- degree histogram ----------------
__global__ void degree_kernel(const int* __restrict__ src, const int* __restrict__ dst,
                              int* __restrict__ deg_out, int* __restrict__ deg_in) {
    int e = blockIdx.x * blockDim.x + threadIdx.x;
    if (e < NE) {
        atomicAdd(&deg_out[src[e]], 1);
        atomicAdd(&deg_in[dst[e]], 1);
    }
}

// ---------------- norms ----------------
__global__ void norm_kernel(const int* __restrict__ deg_out, const int* __restrict__ deg_in,
                            float* __restrict__ norm_out, float* __restrict__ norm_in) {
    int n = blockIdx.x * blockDim.x + threadIdx.x;
    if (n < NN) {
        norm_out[n] = rsqrtf(fmaxf((float)deg_out[n], 1.0f));
        norm_in[n]  = rsqrtf(fmaxf((float)deg_in[n], 1.0f));
    }
}

// ---------------- parallel CSR range allocation ----------------
// Node order in the CSR is irrelevant (ranges just need to be disjoint), so a
// per-block scan + one atomicAdd for the block base replaces the serial scan.
__global__ void alloc_kernel(const int* __restrict__ deg_in, int* __restrict__ row_start,
                             int* __restrict__ cursor, int* __restrict__ counter) {
    __shared__ int smem[256];
    __shared__ int base_s;
    int tid = threadIdx.x;
    int i = blockIdx.x * 256 + tid;
    int v = (i < NN) ? deg_in[i] : 0;
    smem[tid] = v;
    __syncthreads();
    for (int off = 1; off < 256; off <<= 1) {
        int t = (tid >= off) ? smem[tid - off] : 0;
        __syncthreads();
        smem[tid] += t;
        __syncthreads();
    }
    int incl = smem[tid];
    if (tid == 0) base_s = atomicAdd(counter, smem[255]);
    __syncthreads();
    if (i < NN) {
        int excl = base_s + incl - v;
        row_start[i] = excl;
        cursor[i]    = excl;
    }
}

// ---------------- scatter edges into CSR ----------------
__global__ void scatter_kernel(const int* __restrict__ src, const int* __restrict__ dst,
                               int* __restrict__ cursor, int* __restrict__ sorted_src) {
    int e = blockIdx.x * blockDim.x + threadIdx.x;
    if (e < NE) {
        int d = dst[e];
        int pos = atomicAdd(&cursor[d], 1);
        sorted_src[pos] = src[e];
    }
}

// ---------------- per-dst gather-aggregate ----------------
// agg[n,s,f] = sum_{e: dst=n} h[src,s,f]*norm_out[src]
// One block per dst node; lane t owns float4 #t of the 2F-float row.
// 4x edge unroll keeps 4 row-loads (64B/lane) in flight.
template<int F>
__global__ void aggregate_kernel(const float* __restrict__ h,
                                 const int* __restrict__ row_start,
                                 const int* __restrict__ deg_in,
                                 const int* __restrict__ sorted_src,
                                 const float* __restrict__ norm_out,
                                 float* __restrict__ agg) {
    constexpr int F4 = (2 * F) / 4;     // float4 per row (64 or 123)
    int n = blockIdx.x;
    int t = threadIdx.x;
    int beg = row_start[n];
    int end = beg + deg_in[n];
    if (t < F4) {
        const float4* hv = (const float4*)h;
        float4 acc = {0.f, 0.f, 0.f, 0.f};
        int i = beg;
        for (; i + 4 <= end; i += 4) {
            int s0 = sorted_src[i + 0];
            int s1 = sorted_src[i + 1];
            int s2 = sorted_src[i + 2];
            int s3 = sorted_src[i + 3];
            float n0 = norm_out[s0], n1 = norm_out[s1];
            float n2 = norm_out[s2], n3 = norm_out[s3];
            float4 v0 = hv[(size_t)s0 * F4 + t];
            float4 v1 = hv[(size_t)s1 * F4 + t];
            float4 v2 = hv[(size_t)s2 * F4 + t];
            float4 v3 = hv[(size_t)s3 * F4 + t];
            acc.x += v0.x * n0 + v1.x * n1 + v2.x * n2 + v3.x * n3;
            acc.y += v0.y * n0 + v1.y * n1 + v2.y * n2 + v3.y * n3;
            acc.z += v0.z * n0 + v1.z * n1 + v2.z * n2 + v3.z * n3;
            acc.w += v0.w * n0 + v1.w * n1 + v2.w * n2 + v3.w * n3;
        }
        for (; i < end; ++i) {
            int s = sorted_src[i];
            float nr = norm_out[s];
            float4 v = hv[(size_t)s * F4 + t];
            acc.x += v.x * nr;
            acc.y += v.y * nr;
            acc.z += v.z * nr;
            acc.w += v.w * nr;
        }
        ((float4*)agg)[(size_t)n * F4 + t] = acc;
    }
}

// ---------------- register-tiled GEMM ----------------
// out[m,j] = relu( (A[m,:]*norm_in[m/2]) . W[:,j] + b[j] ), j in [0,246)
// BM=64, BN=64, BK=16, 128 threads (tile 8x4). Grid = 625 m-tiles x 4 col-chunks
// = 2500 blocks; consecutive blockIdx share the m-tile (A stays hot in L2).
// FUSE: layer-2 epilogue computes relu -> *fc_w -> mean_s -> atomicAdd(out[n]).
template<int K, bool FUSE>
__global__ __launch_bounds__(128, 4) void gemm_kernel(const float* __restrict__ A,
                                                      const float* __restrict__ W,
                                                      const float* __restrict__ b,
                                                      const float* __restrict__ norm_in,
                                                      float* __restrict__ out,
                                                      const float* __restrict__ fcw,
                                                      const float* __restrict__ fcb) {
    constexpr int BM = 64, BN = 64, BK = 16;
    __shared__ float A_s[BK][BM + 4];
    __shared__ float W_s[BK][BN];

    int tid = threadIdx.x;
    int m0  = (blockIdx.x >> 2) * BM;
    int cb  = (blockIdx.x & 3) * BN;
    int tx  = tid & 15;            // cols cb + 4*tx .. +3
    int ty  = tid >> 4;            // rows m0 + 8*ty .. +7

    float acc[8][4];
#pragma unroll
    for (int r = 0; r < 8; ++r)
#pragma unroll
        for (int c = 0; c < 4; ++c) acc[r][c] = 0.f;

    for (int kt = 0; kt < K; kt += BK) {
        // ---- stage A (64 rows x 16 k), transposed, norm_in fused. 2 float4/thread.
#pragma unroll
        for (int it = 0; it < 2; ++it) {
            int idx = it * 128 + tid;
            int r   = idx >> 2;          // 0..63
            int kk  = (idx & 3) * 4;     // 0,4,8,12
            int m   = m0 + r;
            int kg  = kt + kk;
            float4 v;
            if (kg + 3 < K) {
                v = *(const float4*)(A + (size_t)m * K + kg);
            } else {
                v.x = (kg + 0 < K) ? A[(size_t)m * K + kg + 0] : 0.f;
                v.y = (kg + 1 < K) ? A[(size_t)m * K + kg + 1] : 0.f;
                v.z = (kg + 2 < K) ? A[(size_t)m * K + kg + 2] : 0.f;
                v.w = (kg + 3 < K) ? A[(size_t)m * K + kg + 3] : 0.f;
            }
            float nrm = norm_in[m >> 1];
            A_s[kk + 0][r] = v.x * nrm;
            A_s[kk + 1][r] = v.y * nrm;
            A_s[kk + 2][r] = v.z * nrm;
            A_s[kk + 3][r] = v.w * nrm;
        }
        // ---- stage W (16 k x 64 cols): 2 float4/thread, coalesced
#pragma unroll
        for (int it = 0; it < 2; ++it) {
            int idx = it * 128 + tid;
            int k   = idx >> 4;          // 0..15
            int c4  = (idx & 15) * 4;    // 0..60
            int kg  = kt + k;
            int cc  = cb + c4;
            float4 w;
            if (kg < K) {
                if (cc + 3 < 246) {
                    w = *(const float4*)(W + (size_t)kg * 246 + cc);
                } else {
                    w.x = (cc + 0 < 246) ? W[(size_t)kg * 246 + cc + 0] : 0.f;
                    w.y = (cc + 1 < 246) ? W[(size_t)kg * 246 + cc + 1] : 0.f;
                    w.z = (cc + 2 < 246) ? W[(size_t)kg * 246 + cc + 2] : 0.f;
                    w.w = 0.f;
                }
            } else {
                w.x = w.y = w.z = w.w = 0.f;
            }
            *(float4*)&W_s[k][c4] = w;
        }
        __syncthreads();

#pragma unroll
        for (int k = 0; k < BK; ++k) {
            float4 a0 = *(const float4*)&A_s[k][8 * ty + 0];
            float4 a1 = *(const float4*)&A_s[k][8 * ty + 4];
            float4 w  = *(const float4*)&W_s[k][4 * tx];
            float av[8] = {a0.x, a0.y, a0.z, a0.w, a1.x, a1.y, a1.z, a1.w};
#pragma unroll
            for (int r = 0; r < 8; ++r) {
                acc[r][0] += av[r] * w.x;
                acc[r][1] += av[r] * w.y;
                acc[r][2] += av[r] * w.z;
                acc[r][3] += av[r] * w.w;
            }
        }
        __syncthreads();
    }

    int c0 = cb + 4 * tx;
    float4 bj;
    bj.x = (c0 + 0 < 246) ? b[c0 + 0] : 0.f;
    bj.y = (c0 + 1 < 246) ? b[c0 + 1] : 0.f;
    bj.z = (c0 + 2 < 246) ? b[c0 + 2] : 0.f;
    bj.w = (c0 + 3 < 246) ? b[c0 + 3] : 0.f;

    if (FUSE) {
        // relu -> dot with fc_w (this col-chunk) -> mean over S -> atomicAdd per node
        float4 fw;
        fw.x = (c0 + 0 < 246) ? fcw[c0 + 0] : 0.f;
        fw.y = (c0 + 1 < 246) ? fcw[c0 + 1] : 0.f;
        fw.z = (c0 + 2 < 246) ? fcw[c0 + 2] : 0.f;
        fw.w = (c0 + 3 < 246) ? fcw[c0 + 3] : 0.f;
        float pr[8];
#pragma unroll
        for (int r = 0; r < 8; ++r) {
            float v0 = fmaxf(acc[r][0] + bj.x, 0.f);
            float v1 = fmaxf(acc[r][1] + bj.y, 0.f);
            float v2 = fmaxf(acc[r][2] + bj.z, 0.f);
            float v3 = fmaxf(acc[r][3] + bj.w, 0.f);
            pr[r] = v0 * fw.x + v1 * fw.y + v2 * fw.z + v3 * fw.w;
        }
#pragma unroll
        for (int q = 0; q < 4; ++q) {
            float p = 0.5f * (pr[2 * q] + pr[2 * q + 1]);   // mean over S
#pragma unroll
            for (int off = 8; off > 0; off >>= 1)
                p += __shfl_down(p, off, 16);               // reduce over tx lanes
            if (tx == 0) {
                int n = (m0 + 8 * ty + 2 * q) >> 1;
                if (cb == 0) p += fcb[0];                   // bias added exactly once
                atomicAdd(&out[n], p);
            }
        }
    } else {
#pragma unroll
        for (int r = 0; r < 8; ++r) {
            int m = m0 + 8 * ty + r;
            float* op = out + (size_t)m * 246 + c0;
            float v0 = fmaxf(acc[r][0] + bj.x, 0.f);
            float v1 = fmaxf(acc[r][1] + bj.y, 0.f);
            float v2 = fmaxf(acc[r][2] + bj.z, 0.f);
            float v3 = fmaxf(acc[r][3] + bj.w, 0.f);
            if (c0 + 3 < 246) {
                float4 v = {v0, v1, v2, v3};
                *(float4*)op = v;
            } else {
                if (c0 + 0 < 246) op[0] = v0;
                if (c0 + 1 < 246) op[1] = v1;
                if (c0 + 2 < 246) op[2] = v2;
            }
        }
    }
}

extern "C" void kernel_launch(void* const* d_in, const int* in_sizes, int n_in,
                              void* d_out, int out_size, void* d_ws, size_t ws_size,
                              hipStream_t stream) {
    const float* feat = (const float*)d_in[0];
    const int*   src  = (const int*)d_in[1];
    const int*   dst  = (const int*)d_in[2];
    const float* W0   = (const float*)d_in[3];
    const float* b0   = (const float*)d_in[4];
    const float* W1   = (const float*)d_in[5];
    const float* b1   = (const float*)d_in[6];
    const float* W2   = (const float*)d_in[7];
    const float* b2   = (const float*)d_in[8];
    const float* fcw  = (const float*)d_in[9];
    const float* fcb  = (const float*)d_in[10];
    float* out = (float*)d_out;

    char* ws = (char*)d_ws;
    size_t off = 0;
    auto alloc = [&](size_t bytes) {
        void* p = ws + off;
        off = (off + bytes + 255) & ~(size_t)255;
        return p;
    };
    int*   deg_out_i = (int*)alloc((2 * NN + 64) * sizeof(int));  // deg_out, deg_in, counter
    int*   deg_in_i  = deg_out_i + NN;
    int*   counter   = deg_out_i + 2 * NN;
    int*   row_start = (int*)alloc(NN * sizeof(int));
    int*   cursor    = (int*)alloc(NN * sizeof(int));
    int*   sorted    = (int*)alloc(NE * sizeof(int));
    float* norm_out  = (float*)alloc(NN * sizeof(float));
    float* norm_in   = (float*)alloc(NN * sizeof(float));
    float* bufA      = (float*)alloc((size_t)NN * SS * FH * sizeof(float));
    float* bufB      = (float*)alloc((size_t)NN * SS * FH * sizeof(float));

    // zero degree counters + alloc counter + output accumulator
    hipMemsetAsync(deg_out_i, 0, (2 * NN + 1) * sizeof(int), stream);
    hipMemsetAsync(out, 0, NN * sizeof(float), stream);

    degree_kernel<<<(NE + 255) / 256, 256, 0, stream>>>(src, dst, deg_out_i, deg_in_i);
    norm_kernel<<<(NN + 255) / 256, 256, 0, stream>>>(deg_out_i, deg_in_i, norm_out, norm_in);
    alloc_kernel<<<(NN + 255) / 256, 256, 0, stream>>>(deg_in_i, row_start, cursor, counter);
    scatter_kernel<<<(NE + 255) / 256, 256, 0, stream>>>(src, dst, cursor, sorted);

    const int ggrid = (NN * SS / 64) * 4;   // 2500 blocks

    // Layer 0: feat [N,S,128] -> agg(bufA) -> gemm -> h1(bufB)
    aggregate_kernel<FIN><<<NN, 64, 0, stream>>>(feat, row_start, deg_in_i, sorted, norm_out, bufA);
    gemm_kernel<FIN, false><<<ggrid, 128, 0, stream>>>(bufA, W0, b0, norm_in, bufB, fcw, fcb);

    // Layer 1
    aggregate_kernel<FH><<<NN, 128, 0, stream>>>(bufB, row_start, deg_in_i, sorted, norm_out, bufA);
    gemm_kernel<FH, false><<<ggrid, 128, 0, stream>>>(bufA, W1, b1, norm_in, bufB, fcw, fcb);

    // Layer 2: gemm fused with relu+mean_s+fc -> out
    aggregate_kernel<FH><<<NN, 128, 0, stream>>>(bufB, row_start, deg_in_i, sorted, norm_out, bufA);
    gemm_kernel<FH, true><<<ggrid, 128, 0, stream>>>(bufA, W2, b2, norm_in, out, fcw, fcb);
}